// Round 1
// baseline (1995.029 us; speedup 1.0000x reference)
//
#include <hip/hip_runtime.h>
#include <hip/hip_bf16.h>

#define GG 128
#define G2 (GG*GG)
#define CC 256
#define HH 4
#define NPTS 100000
#define NB 2
#define LN_EPS 1e-5f

// ---- sortable-uint encoding for float atomicMax ----
__device__ __forceinline__ unsigned encf(float f){
    unsigned u = __float_as_uint(f);
    return (u & 0x80000000u) ? ~u : (u | 0x80000000u);
}
__device__ __forceinline__ float decf(unsigned u){
    return __uint_as_float((u & 0x80000000u) ? (u ^ 0x80000000u) : ~u);
}

__global__ __launch_bounds__(256) void init_smax_kernel(unsigned* __restrict__ smax){
    int i = blockIdx.x * 256 + threadIdx.x;
    if (i < NB*3*G2*HH) smax[i] = 0x007FFFFFu; // enc(-inf)
}

__global__ __launch_bounds__(256) void transpose_w_kernel(
    const float* __restrict__ Wk, const float* __restrict__ Wv,
    float* __restrict__ WkT, float* __restrict__ WvT)
{
    int m = blockIdx.x >> 8;
    int k = blockIdx.x & 255;
    int c = threadIdx.x;
    if (m == 0) WkT[k*CC + c] = Wk[c*CC + k];
    else        WvT[k*CC + c] = Wv[c*CC + k];
}

// q (C, G2)  ->  qT[plane][cell][c]
__global__ __launch_bounds__(256) void transpose_q_kernel(
    const float* __restrict__ qxy, const float* __restrict__ qxz,
    const float* __restrict__ qyz, float* __restrict__ qT)
{
    int blk = blockIdx.x;
    int plane = blk >> 10;          // 1024 tiles per plane
    int rem = blk & 1023;
    int cell0 = (rem >> 2) << 6;    // 256 cell-tiles
    int c0 = (rem & 3) << 6;        // 4 c-tiles
    const float* q = plane == 0 ? qxy : (plane == 1 ? qxz : qyz);
    __shared__ float tile[64][65];
    int tx = threadIdx.x & 63;
    int ty = threadIdx.x >> 6;
    #pragma unroll
    for (int i = ty; i < 64; i += 4)
        tile[i][tx] = q[(size_t)(c0 + i)*G2 + cell0 + tx];
    __syncthreads();
    #pragma unroll
    for (int i = ty; i < 64; i += 4)
        qT[((size_t)plane*G2 + cell0 + i)*CC + c0 + tx] = tile[tx][i];
}

// Fused: coords + LN + K/V matvec + per-plane s & segment-max.
// 16 points per block; 4 waves; wave w owns points 4w..4w+3 for LN & stage-3.
__global__ __launch_bounds__(256) void point_kernel(
    const float* __restrict__ feats, const float* __restrict__ bounds,
    const float* __restrict__ WkT, const float* __restrict__ kbias,
    const float* __restrict__ WvT, const float* __restrict__ vbias,
    const float* __restrict__ lng, const float* __restrict__ lnb,
    const float* __restrict__ qT,
    __hip_bfloat16* __restrict__ Vout, float* __restrict__ s_out,
    int* __restrict__ idx_out, unsigned* __restrict__ smax)
{
    __shared__ __align__(16) float fn_t[CC][20]; // [k][point], padded stride 20
    __shared__ float K_lds[16][CC];

    int t = threadIdx.x;
    int lane = t & 63;
    int w = t >> 6;
    long long g0 = (long long)blockIdx.x * 16;
    int b  = (int)(g0 / NPTS);
    int pt0 = (int)(g0 % NPTS);

    float cxyz[4][3];

    // ---- stage 1: coords + LayerNorm ----
    #pragma unroll
    for (int r = 0; r < 4; r++){
        int p = w*4 + r;
        const float* f = feats + ((size_t)b*NPTS + pt0 + p)*CC;
        float x0 = f[lane];
        float x1 = f[lane + 64];
        float x2 = f[lane + 128];
        float x3 = f[lane + 192];
        float cv = 0.f;
        if (lane < 3){
            float l0 = bounds[2*lane], h0 = bounds[2*lane+1];
            // match numpy: (2*(x-lo))/(hi-lo) - 1, rn ops, no fma
            float tnum = __fmul_rn(2.0f, __fsub_rn(x0, l0));
            cv = __fsub_rn(__fdiv_rn(tnum, __fsub_rn(h0, l0)), 1.0f);
        }
        float cx = __shfl(cv, 0), cy = __shfl(cv, 1), cz = __shfl(cv, 2);
        if (lane < 3) x0 = cv;
        cxyz[r][0] = cx; cxyz[r][1] = cy; cxyz[r][2] = cz;

        float s1 = x0 + x1 + x2 + x3;
        float s2 = x0*x0 + x1*x1 + x2*x2 + x3*x3;
        #pragma unroll
        for (int off = 32; off; off >>= 1){
            s1 += __shfl_xor(s1, off);
            s2 += __shfl_xor(s2, off);
        }
        float mu = s1 * (1.0f/CC);
        float var = s2 * (1.0f/CC) - mu*mu;
        float rs = rsqrtf(var + LN_EPS);
        fn_t[lane      ][p] = (x0 - mu)*rs*lng[lane      ] + lnb[lane      ];
        fn_t[lane +  64][p] = (x1 - mu)*rs*lng[lane +  64] + lnb[lane +  64];
        fn_t[lane + 128][p] = (x2 - mu)*rs*lng[lane + 128] + lnb[lane + 128];
        fn_t[lane + 192][p] = (x3 - mu)*rs*lng[lane + 192] + lnb[lane + 192];
    }
    __syncthreads();

    // ---- stage 2: K/V matvec, thread t owns output channel t ----
    float ak[16], av[16];
    {
        float bk = kbias[t], bv = vbias[t];
        #pragma unroll
        for (int p = 0; p < 16; p++){ ak[p] = bk; av[p] = bv; }
    }
    #pragma unroll 2
    for (int k = 0; k < CC; k++){
        float wk = WkT[k*CC + t];
        float wv = WvT[k*CC + t];
        const float4* fp = reinterpret_cast<const float4*>(&fn_t[k][0]);
        float4 q0 = fp[0], q1 = fp[1], q2 = fp[2], q3 = fp[3];
        float fv[16];
        fv[0]=q0.x; fv[1]=q0.y; fv[2]=q0.z; fv[3]=q0.w;
        fv[4]=q1.x; fv[5]=q1.y; fv[6]=q1.z; fv[7]=q1.w;
        fv[8]=q2.x; fv[9]=q2.y; fv[10]=q2.z; fv[11]=q2.w;
        fv[12]=q3.x; fv[13]=q3.y; fv[14]=q3.z; fv[15]=q3.w;
        #pragma unroll
        for (int p = 0; p < 16; p++){
            ak[p] = fmaf(fv[p], wk, ak[p]);
            av[p] = fmaf(fv[p], wv, av[p]);
        }
    }
    #pragma unroll
    for (int p = 0; p < 16; p++){
        K_lds[p][t] = ak[p];
        Vout[((size_t)b*NPTS + pt0 + p)*CC + t] = __float2bfloat16(av[p]);
    }
    __syncthreads();

    // ---- stage 3: per-plane s + segment max ----
    #pragma unroll
    for (int r = 0; r < 4; r++){
        int p = w*4 + r;
        int pt = pt0 + p;
        float k0 = K_lds[p][lane];
        float k1 = K_lds[p][lane + 64];
        float k2 = K_lds[p][lane + 128];
        float k3 = K_lds[p][lane + 192];
        float cx = cxyz[r][0], cy = cxyz[r][1], cz = cxyz[r][2];
        #pragma unroll
        for (int pl = 0; pl < 3; pl++){
            float a = (pl == 2) ? cy : cx;
            float bb = (pl == 0) ? cy : cz;
            // match numpy: trunc((a*0.5+0.5)*127), rn ops, no fma
            float ua = __fmul_rn(__fadd_rn(__fmul_rn(a, 0.5f), 0.5f), (float)(GG-1));
            float ub = __fmul_rn(__fadd_rn(__fmul_rn(bb,0.5f), 0.5f), (float)(GG-1));
            int gx = (int)ua; gx = gx < 0 ? 0 : (gx > GG-1 ? GG-1 : gx);
            int gy = (int)ub; gy = gy < 0 ? 0 : (gy > GG-1 ? GG-1 : gy);
            int cell = gx*GG + gy;
            const float* qrow = qT + ((size_t)pl*G2 + cell)*CC;
            float sp0 = k0 * qrow[lane];
            float sp1 = k1 * qrow[lane + 64];
            float sp2 = k2 * qrow[lane + 128];
            float sp3 = k3 * qrow[lane + 192];
            #pragma unroll
            for (int off = 32; off; off >>= 1){
                sp0 += __shfl_xor(sp0, off);
                sp1 += __shfl_xor(sp1, off);
                sp2 += __shfl_xor(sp2, off);
                sp3 += __shfl_xor(sp3, off);
            }
            if (lane == 0){
                int bp = b*3 + pl;
                size_t sbase = ((size_t)bp*NPTS + pt)*HH;
                s_out[sbase + 0] = sp0;
                s_out[sbase + 1] = sp1;
                s_out[sbase + 2] = sp2;
                s_out[sbase + 3] = sp3;
                size_t mbase = ((size_t)bp*G2 + cell)*HH;
                atomicMax((unsigned int*)&smax[mbase + 0], encf(sp0));
                atomicMax((unsigned int*)&smax[mbase + 1], encf(sp1));
                atomicMax((unsigned int*)&smax[mbase + 2], encf(sp2));
                atomicMax((unsigned int*)&smax[mbase + 3], encf(sp3));
                idx_out[(size_t)bp*NPTS + pt] = cell;
            }
        }
    }
}

// e = exp(s - smax); atomicAdd den and e*v into d_out
__global__ __launch_bounds__(256) void scatter_kernel(
    const float* __restrict__ s_in, const int* __restrict__ idx_in,
    const unsigned* __restrict__ smax, const __hip_bfloat16* __restrict__ V,
    float* __restrict__ out, float* __restrict__ den)
{
    int t = threadIdx.x;
    int lane = t & 63;
    int w = t >> 6;
    long long g = (long long)blockIdx.x * 4 + w; // over NB*3*NPTS
    int bp = (int)(g / NPTS);
    int pt = (int)(g % NPTS);
    int b = bp / 3;

    int cell = idx_in[(size_t)bp*NPTS + pt];
    size_t sbase = ((size_t)bp*NPTS + pt)*HH;
    size_t mbase = ((size_t)bp*G2 + cell)*HH;
    float e0 = expf(s_in[sbase + 0] - decf(smax[mbase + 0]));
    float e1 = expf(s_in[sbase + 1] - decf(smax[mbase + 1]));
    float e2 = expf(s_in[sbase + 2] - decf(smax[mbase + 2]));
    float e3 = expf(s_in[sbase + 3] - decf(smax[mbase + 3]));

    const __hip_bfloat16* vp = V + ((size_t)b*NPTS + pt)*CC;
    float* outp = out + ((size_t)bp*G2 + cell)*CC;
    atomicAdd(&outp[lane      ], e0 * __bfloat162float(vp[lane      ]));
    atomicAdd(&outp[lane +  64], e1 * __bfloat162float(vp[lane +  64]));
    atomicAdd(&outp[lane + 128], e2 * __bfloat162float(vp[lane + 128]));
    atomicAdd(&outp[lane + 192], e3 * __bfloat162float(vp[lane + 192]));
    if (lane == 0){
        atomicAdd(&den[mbase + 0], e0);
        atomicAdd(&den[mbase + 1], e1);
        atomicAdd(&den[mbase + 2], e2);
        atomicAdd(&den[mbase + 3], e3);
    }
}

__global__ __launch_bounds__(256) void normalize_kernel(
    float* __restrict__ out, const float* __restrict__ den)
{
    size_t i = (size_t)blockIdx.x * 256 + threadIdx.x; // over NB*3*G2*CC
    size_t cellg = i >> 8;          // bp*G2 + cell
    int c = (int)(i & 255);
    float d = den[cellg*HH + (c >> 6)];
    out[i] = out[i] / fmaxf(d, 1e-30f);
}

extern "C" void kernel_launch(void* const* d_in, const int* in_sizes, int n_in,
                              void* d_out, int out_size, void* d_ws, size_t ws_size,
                              hipStream_t stream)
{
    const float* feats  = (const float*)d_in[0];
    const float* bounds = (const float*)d_in[1];
    const float* qxy = (const float*)d_in[2];
    const float* qxz = (const float*)d_in[3];
    const float* qyz = (const float*)d_in[4];
    const float* Wk  = (const float*)d_in[5];
    const float* kb  = (const float*)d_in[6];
    const float* Wv  = (const float*)d_in[7];
    const float* vb  = (const float*)d_in[8];
    const float* lng = (const float*)d_in[9];
    const float* lnb = (const float*)d_in[10];

    char* ws = (char*)d_ws;
    float* qT            = (float*)(ws);                    // 50,331,648 B
    float* WkT           = (float*)(ws + 50331648);         //    262,144 B
    float* WvT           = (float*)(ws + 50593792);         //    262,144 B
    __hip_bfloat16* Vbuf = (__hip_bfloat16*)(ws + 50855936);// 102,400,000 B
    float* s_buf         = (float*)(ws + 153255936);        //  9,600,000 B
    int*   idx_buf       = (int*)(ws + 162855936);          //  2,400,000 B
    unsigned* smax       = (unsigned*)(ws + 165255936);     //  1,572,864 B
    float* den           = (float*)(ws + 166828800);        //  1,572,864 B
    if (ws_size < 168401664ull) return;                     // loud failure if ws too small

    hipMemsetAsync(d_out, 0, (size_t)out_size * sizeof(float), stream);
    hipMemsetAsync(den, 0, (size_t)NB*3*G2*HH * sizeof(float), stream);
    init_smax_kernel<<<1536, 256, 0, stream>>>(smax);
    transpose_w_kernel<<<512, 256, 0, stream>>>(Wk, Wv, WkT, WvT);
    transpose_q_kernel<<<3072, 256, 0, stream>>>(qxy, qxz, qyz, qT);
    point_kernel<<<12500, 256, 0, stream>>>(feats, bounds, WkT, kb, WvT, vb,
                                            lng, lnb, qT, Vbuf, s_buf, idx_buf, smax);
    scatter_kernel<<<150000, 256, 0, stream>>>(s_buf, idx_buf, smax, Vbuf,
                                               (float*)d_out, den);
    normalize_kernel<<<98304, 256, 0, stream>>>((float*)d_out, den);
}

// Round 2
// 1609.934 us; speedup vs baseline: 1.2392x; 1.2392x over previous
//
#include <hip/hip_runtime.h>
#include <hip/hip_bf16.h>

#define GG 128
#define G2 (GG*GG)
#define CC 256
#define HH 4
#define NPTS 100000
#define NB 2
#define LN_EPS 1e-5f

// ---- sortable-uint encoding for float atomicMax ----
__device__ __forceinline__ unsigned encf(float f){
    unsigned u = __float_as_uint(f);
    return (u & 0x80000000u) ? ~u : (u | 0x80000000u);
}
__device__ __forceinline__ float decf(unsigned u){
    return __uint_as_float((u & 0x80000000u) ? (u ^ 0x80000000u) : ~u);
}

__global__ __launch_bounds__(256) void init_smax_kernel(unsigned* __restrict__ smax){
    int i = blockIdx.x * 256 + threadIdx.x;
    if (i < NB*3*G2*HH) smax[i] = 0x007FFFFFu; // enc(-inf)
}

__global__ __launch_bounds__(256) void transpose_w_kernel(
    const float* __restrict__ Wk, const float* __restrict__ Wv,
    float* __restrict__ WkT, float* __restrict__ WvT)
{
    int m = blockIdx.x >> 8;
    int k = blockIdx.x & 255;
    int c = threadIdx.x;
    if (m == 0) WkT[k*CC + c] = Wk[c*CC + k];
    else        WvT[k*CC + c] = Wv[c*CC + k];
}

// q (C, G2)  ->  qT[plane][cell][c]
__global__ __launch_bounds__(256) void transpose_q_kernel(
    const float* __restrict__ qxy, const float* __restrict__ qxz,
    const float* __restrict__ qyz, float* __restrict__ qT)
{
    int blk = blockIdx.x;
    int plane = blk >> 10;          // 1024 tiles per plane
    int rem = blk & 1023;
    int cell0 = (rem >> 2) << 6;    // 256 cell-tiles
    int c0 = (rem & 3) << 6;        // 4 c-tiles
    const float* q = plane == 0 ? qxy : (plane == 1 ? qxz : qyz);
    __shared__ float tile[64][65];
    int tx = threadIdx.x & 63;
    int ty = threadIdx.x >> 6;
    #pragma unroll
    for (int i = ty; i < 64; i += 4)
        tile[i][tx] = q[(size_t)(c0 + i)*G2 + cell0 + tx];
    __syncthreads();
    #pragma unroll
    for (int i = ty; i < 64; i += 4)
        qT[((size_t)plane*G2 + cell0 + i)*CC + c0 + tx] = tile[tx][i];
}

// Fused: coords + LN + K/V matvec + per-plane s & segment-max + cell counts.
__global__ __launch_bounds__(256) void point_kernel(
    const float* __restrict__ feats, const float* __restrict__ bounds,
    const float* __restrict__ WkT, const float* __restrict__ kbias,
    const float* __restrict__ WvT, const float* __restrict__ vbias,
    const float* __restrict__ lng, const float* __restrict__ lnb,
    const float* __restrict__ qT,
    __hip_bfloat16* __restrict__ Vout, float* __restrict__ s_out,
    unsigned* __restrict__ smax, int* __restrict__ cnt)
{
    __shared__ __align__(16) float fn_t[CC][20]; // [k][point], padded stride 20
    __shared__ float K_lds[16][CC];

    int t = threadIdx.x;
    int lane = t & 63;
    int w = t >> 6;
    long long g0 = (long long)blockIdx.x * 16;
    int b  = (int)(g0 / NPTS);
    int pt0 = (int)(g0 % NPTS);

    float cxyz[4][3];

    // ---- stage 1: coords + LayerNorm ----
    #pragma unroll
    for (int r = 0; r < 4; r++){
        int p = w*4 + r;
        const float* f = feats + ((size_t)b*NPTS + pt0 + p)*CC;
        float x0 = f[lane];
        float x1 = f[lane + 64];
        float x2 = f[lane + 128];
        float x3 = f[lane + 192];
        float cv = 0.f;
        if (lane < 3){
            float l0 = bounds[2*lane], h0 = bounds[2*lane+1];
            float tnum = __fmul_rn(2.0f, __fsub_rn(x0, l0));
            cv = __fsub_rn(__fdiv_rn(tnum, __fsub_rn(h0, l0)), 1.0f);
        }
        float cx = __shfl(cv, 0), cy = __shfl(cv, 1), cz = __shfl(cv, 2);
        if (lane < 3) x0 = cv;
        cxyz[r][0] = cx; cxyz[r][1] = cy; cxyz[r][2] = cz;

        float s1 = x0 + x1 + x2 + x3;
        float s2 = x0*x0 + x1*x1 + x2*x2 + x3*x3;
        #pragma unroll
        for (int off = 32; off; off >>= 1){
            s1 += __shfl_xor(s1, off);
            s2 += __shfl_xor(s2, off);
        }
        float mu = s1 * (1.0f/CC);
        float var = s2 * (1.0f/CC) - mu*mu;
        float rs = rsqrtf(var + LN_EPS);
        fn_t[lane      ][p] = (x0 - mu)*rs*lng[lane      ] + lnb[lane      ];
        fn_t[lane +  64][p] = (x1 - mu)*rs*lng[lane +  64] + lnb[lane +  64];
        fn_t[lane + 128][p] = (x2 - mu)*rs*lng[lane + 128] + lnb[lane + 128];
        fn_t[lane + 192][p] = (x3 - mu)*rs*lng[lane + 192] + lnb[lane + 192];
    }
    __syncthreads();

    // ---- stage 2: K/V matvec, thread t owns output channel t ----
    float ak[16], av[16];
    {
        float bk = kbias[t], bv = vbias[t];
        #pragma unroll
        for (int p = 0; p < 16; p++){ ak[p] = bk; av[p] = bv; }
    }
    #pragma unroll 2
    for (int k = 0; k < CC; k++){
        float wk = WkT[k*CC + t];
        float wv = WvT[k*CC + t];
        const float4* fp = reinterpret_cast<const float4*>(&fn_t[k][0]);
        float4 q0 = fp[0], q1 = fp[1], q2 = fp[2], q3 = fp[3];
        float fv[16];
        fv[0]=q0.x; fv[1]=q0.y; fv[2]=q0.z; fv[3]=q0.w;
        fv[4]=q1.x; fv[5]=q1.y; fv[6]=q1.z; fv[7]=q1.w;
        fv[8]=q2.x; fv[9]=q2.y; fv[10]=q2.z; fv[11]=q2.w;
        fv[12]=q3.x; fv[13]=q3.y; fv[14]=q3.z; fv[15]=q3.w;
        #pragma unroll
        for (int p = 0; p < 16; p++){
            ak[p] = fmaf(fv[p], wk, ak[p]);
            av[p] = fmaf(fv[p], wv, av[p]);
        }
    }
    #pragma unroll
    for (int p = 0; p < 16; p++){
        K_lds[p][t] = ak[p];
        Vout[((size_t)b*NPTS + pt0 + p)*CC + t] = __float2bfloat16(av[p]);
    }
    __syncthreads();

    // ---- stage 3: per-plane s + segment max + counts ----
    #pragma unroll
    for (int r = 0; r < 4; r++){
        int p = w*4 + r;
        int pt = pt0 + p;
        float k0 = K_lds[p][lane];
        float k1 = K_lds[p][lane + 64];
        float k2 = K_lds[p][lane + 128];
        float k3 = K_lds[p][lane + 192];
        float cx = cxyz[r][0], cy = cxyz[r][1], cz = cxyz[r][2];
        #pragma unroll
        for (int pl = 0; pl < 3; pl++){
            float a = (pl == 2) ? cy : cx;
            float bb = (pl == 0) ? cy : cz;
            float ua = __fmul_rn(__fadd_rn(__fmul_rn(a, 0.5f), 0.5f), (float)(GG-1));
            float ub = __fmul_rn(__fadd_rn(__fmul_rn(bb,0.5f), 0.5f), (float)(GG-1));
            int gx = (int)ua; gx = gx < 0 ? 0 : (gx > GG-1 ? GG-1 : gx);
            int gy = (int)ub; gy = gy < 0 ? 0 : (gy > GG-1 ? GG-1 : gy);
            int cell = gx*GG + gy;
            const float* qrow = qT + ((size_t)pl*G2 + cell)*CC;
            float sp0 = k0 * qrow[lane];
            float sp1 = k1 * qrow[lane + 64];
            float sp2 = k2 * qrow[lane + 128];
            float sp3 = k3 * qrow[lane + 192];
            #pragma unroll
            for (int off = 32; off; off >>= 1){
                sp0 += __shfl_xor(sp0, off);
                sp1 += __shfl_xor(sp1, off);
                sp2 += __shfl_xor(sp2, off);
                sp3 += __shfl_xor(sp3, off);
            }
            if (lane == 0){
                int bp = b*3 + pl;
                size_t sbase = ((size_t)bp*NPTS + pt)*HH;
                s_out[sbase + 0] = sp0;
                s_out[sbase + 1] = sp1;
                s_out[sbase + 2] = sp2;
                s_out[sbase + 3] = sp3;
                size_t mbase = ((size_t)bp*G2 + cell)*HH;
                atomicMax((unsigned int*)&smax[mbase + 0], encf(sp0));
                atomicMax((unsigned int*)&smax[mbase + 1], encf(sp1));
                atomicMax((unsigned int*)&smax[mbase + 2], encf(sp2));
                atomicMax((unsigned int*)&smax[mbase + 3], encf(sp3));
                atomicAdd(&cnt[(size_t)bp*G2 + cell], 1);
            }
        }
    }
}

// exclusive scan of cnt[98304] -> startm[98304]; single block of 1024
__global__ __launch_bounds__(1024) void scan_kernel(
    const int* __restrict__ cnt, int* __restrict__ startm)
{
    __shared__ int sums[1024];
    const int PER = (NB*3*G2) / 1024; // 96
    int t = threadIdx.x;
    int base = t * PER;
    int s = 0;
    for (int i = 0; i < PER; i++) s += cnt[base + i];
    sums[t] = s;
    __syncthreads();
    for (int off = 1; off < 1024; off <<= 1){
        int v = (t >= off) ? sums[t - off] : 0;
        __syncthreads();
        sums[t] += v;
        __syncthreads();
    }
    int excl = (t == 0) ? 0 : sums[t - 1];
    for (int i = 0; i < PER; i++){
        int c = cnt[base + i];
        startm[base + i] = excl;
        excl += c;
    }
}

// bin point ids per cell; mutates startm (start -> end)
__global__ __launch_bounds__(256) void fill_kernel(
    const float* __restrict__ feats, const float* __restrict__ bounds,
    int* __restrict__ startm, int* __restrict__ plist)
{
    int g = blockIdx.x * 256 + threadIdx.x; // over NB*NPTS
    if (g >= NB*NPTS) return;
    int b = g / NPTS, pt = g % NPTS;
    const float* f = feats + (size_t)g*CC;
    float c3[3];
    #pragma unroll
    for (int a = 0; a < 3; a++){
        float lo = bounds[2*a], hi = bounds[2*a+1];
        float tnum = __fmul_rn(2.0f, __fsub_rn(f[a], lo));
        c3[a] = __fsub_rn(__fdiv_rn(tnum, __fsub_rn(hi, lo)), 1.0f);
    }
    #pragma unroll
    for (int pl = 0; pl < 3; pl++){
        float a = (pl == 2) ? c3[1] : c3[0];
        float bb = (pl == 0) ? c3[1] : c3[2];
        float ua = __fmul_rn(__fadd_rn(__fmul_rn(a, 0.5f), 0.5f), (float)(GG-1));
        float ub = __fmul_rn(__fadd_rn(__fmul_rn(bb,0.5f), 0.5f), (float)(GG-1));
        int gx = (int)ua; gx = gx < 0 ? 0 : (gx > GG-1 ? GG-1 : gx);
        int gy = (int)ub; gy = gy < 0 ? 0 : (gy > GG-1 ? GG-1 : gy);
        int cellg = (b*3 + pl)*G2 + gx*GG + gy;
        int pos = atomicAdd(&startm[cellg], 1);
        plist[pos] = pt;
    }
}

// one block per (bp, cell): gather its points, local softmax-denominator,
// accumulate e*v in registers, fused normalize, single store. No atomics.
__global__ __launch_bounds__(256) void gather_kernel(
    const int* __restrict__ plist, const int* __restrict__ startm,
    const int* __restrict__ cnt, const float* __restrict__ s_in,
    const unsigned* __restrict__ smax, const __hip_bfloat16* __restrict__ V,
    float* __restrict__ out)
{
    int cellg = blockIdx.x;            // bp*G2 + cell
    int bp = cellg >> 14;              // /G2
    int b = bp / 3;
    int t = threadIdx.x;
    int h = t >> 6;

    int end = startm[cellg];           // mutated by fill: start+count
    int n = cnt[cellg];
    int begin = end - n;

    __shared__ float e_lds[64*HH];
    __shared__ int pt_lds[64];

    float acc = 0.f, den = 0.f;
    const __hip_bfloat16* Vb = V + (size_t)b*NPTS*CC;
    const float* sb = s_in + (size_t)bp*NPTS*HH;

    for (int chunk = begin; chunk < end; chunk += 64){
        int m = min(64, end - chunk);
        if (t < m) pt_lds[t] = plist[chunk + t];
        if (t < 4*m){
            int pt = plist[chunk + (t >> 2)];
            float smh = decf(smax[(size_t)cellg*HH + (t & 3)]);
            e_lds[t] = expf(sb[(size_t)pt*HH + (t & 3)] - smh);
        }
        __syncthreads();
        int j = 0;
        for (; j + 4 <= m; j += 4){
            int p0 = pt_lds[j], p1 = pt_lds[j+1], p2 = pt_lds[j+2], p3 = pt_lds[j+3];
            float e0 = e_lds[(j  )*4 + h], e1 = e_lds[(j+1)*4 + h];
            float e2 = e_lds[(j+2)*4 + h], e3 = e_lds[(j+3)*4 + h];
            float v0 = __bfloat162float(Vb[(size_t)p0*CC + t]);
            float v1 = __bfloat162float(Vb[(size_t)p1*CC + t]);
            float v2 = __bfloat162float(Vb[(size_t)p2*CC + t]);
            float v3 = __bfloat162float(Vb[(size_t)p3*CC + t]);
            acc = fmaf(e0, v0, acc); acc = fmaf(e1, v1, acc);
            acc = fmaf(e2, v2, acc); acc = fmaf(e3, v3, acc);
            den += (e0 + e1) + (e2 + e3);
        }
        for (; j < m; ++j){
            float e = e_lds[j*4 + h];
            acc = fmaf(e, __bfloat162float(Vb[(size_t)pt_lds[j]*CC + t]), acc);
            den += e;
        }
        __syncthreads();
    }
    out[(size_t)cellg*CC + t] = acc / fmaxf(den, 1e-30f);
}

extern "C" void kernel_launch(void* const* d_in, const int* in_sizes, int n_in,
                              void* d_out, int out_size, void* d_ws, size_t ws_size,
                              hipStream_t stream)
{
    const float* feats  = (const float*)d_in[0];
    const float* bounds = (const float*)d_in[1];
    const float* qxy = (const float*)d_in[2];
    const float* qxz = (const float*)d_in[3];
    const float* qyz = (const float*)d_in[4];
    const float* Wk  = (const float*)d_in[5];
    const float* kb  = (const float*)d_in[6];
    const float* Wv  = (const float*)d_in[7];
    const float* vb  = (const float*)d_in[8];
    const float* lng = (const float*)d_in[9];
    const float* lnb = (const float*)d_in[10];

    char* ws = (char*)d_ws;
    float* qT            = (float*)(ws);                    // 50,331,648 B
    float* WkT           = (float*)(ws + 50331648);         //    262,144 B
    float* WvT           = (float*)(ws + 50593792);         //    262,144 B
    __hip_bfloat16* Vbuf = (__hip_bfloat16*)(ws + 50855936);// 102,400,000 B
    float* s_buf         = (float*)(ws + 153255936);        //  9,600,000 B
    unsigned* smax       = (unsigned*)(ws + 162855936);     //  1,572,864 B
    int* cnt             = (int*)(ws + 164428800);          //    393,216 B
    int* startm          = (int*)(ws + 164822016);          //    393,216 B
    int* plist           = (int*)(ws + 165215232);          //  2,400,000 B
    if (ws_size < 167615232ull) return;                     // total 167.6 MB

    hipMemsetAsync(cnt, 0, (size_t)NB*3*G2*sizeof(int), stream);
    init_smax_kernel<<<1536, 256, 0, stream>>>(smax);
    transpose_w_kernel<<<512, 256, 0, stream>>>(Wk, Wv, WkT, WvT);
    transpose_q_kernel<<<3072, 256, 0, stream>>>(qxy, qxz, qyz, qT);
    point_kernel<<<12500, 256, 0, stream>>>(feats, bounds, WkT, kb, WvT, vb,
                                            lng, lnb, qT, Vbuf, s_buf, smax, cnt);
    scan_kernel<<<1, 1024, 0, stream>>>(cnt, startm);
    fill_kernel<<<(NB*NPTS + 255)/256, 256, 0, stream>>>(feats, bounds, startm, plist);
    gather_kernel<<<NB*3*G2, 256, 0, stream>>>(plist, startm, cnt, s_buf, smax,
                                               Vbuf, (float*)d_out);
}